// Round 5
// baseline (612.514 us; speedup 1.0000x reference)
//
#include <hip/hip_runtime.h>
#include <hip/hip_cooperative_groups.h>
#include <math.h>

namespace cg = cooperative_groups;

#define NN 200
#define DD 8
#define HH 128
#define NHEAD 4
#define HDIM 32
#define LL 6
#define EE 16384
#define SS 8
#define FFD 512
#define W64 256                  // EE/64 bitmap words per node column

#define WSCALE 1048576.0f        // 2^20 fixed-point scale for LDS int attention atomics
#define WNORM  (1.0f/1048576.0f)
#define RSCALE 0.17677669529663687f   // 1/sqrt(32)

struct P {
    const float *x; const int *hedges;
    const float *Wi, *bi, *lnig, *lnib;
    const float *Wc, *bc, *Wq, *bq, *Wk, *bk, *Wv, *bv, *Wo, *bo;
    const float *n1g, *n1b, *n2g, *n2b, *Wf1, *bf1, *Wf2, *bf2;
    const float *Wh1, *bh1, *Wh2, *bh2, *Wh3, *bh3, *We, *be;
    float *out, *h, *hc, *K, *V;
    unsigned long long *bmT;
};

__device__ __forceinline__ float geluf(float x) {
    return 0.5f * x * (1.0f + erff(x * 0.70710678118654752f));
}
__device__ __forceinline__ float softplusf(float x) {
    return (x > 20.0f) ? x : log1pf(expf(x));
}
__device__ __forceinline__ void ln_reduce(const float* sv, const float* sv2, float* mred, int tid) {
    if (tid < 64) {
        float s1 = sv[tid] + sv[tid + 64];
        float s2 = sv2[tid] + sv2[tid + 64];
        #pragma unroll
        for (int m = 32; m > 0; m >>= 1) {
            s1 += __shfl_xor(s1, m);
            s2 += __shfl_xor(s2, m);
        }
        if (tid == 0) { mred[0] = s1 * (1.0f / HH); mred[1] = s2 * (1.0f / HH); }
    }
}

__launch_bounds__(512)
__global__ void k_coop(P p) {
    cg::grid_group grid = cg::this_grid();
    __shared__ unsigned long long colA[W64];
    __shared__ float Gs[NN];
    __shared__ int list[1024];
    __shared__ float hrow[HH], row[HH], Qs[HH];
    __shared__ float Ts[NHEAD * NN];
    __shared__ int Wrow[NHEAD * NN];
    __shared__ float psA[4][HH], psB[4][HH], psC[4][HH];
    __shared__ float sv[HH], sv2[HH], mred[2];
    __shared__ float aggs[HH], h2s[HH];
    __shared__ float ts[FFD];
    __shared__ int wsum[8];
    __shared__ int wtot;

    const int a = blockIdx.x, tid = threadIdx.x;
    const int j = tid & 127, kq = tid >> 7;

    // ---- prologue 1: build own bitmap column from hedges (LDS atomicOr)
    for (int w = tid; w < W64; w += 512) colA[w] = 0ULL;
    __syncthreads();
    {
        const int4* he4 = (const int4*)p.hedges;
        for (int i4 = tid; i4 < EE * SS / 4; i4 += 512) {
            int4 v = he4[i4];
            if (v.x == a || v.y == a || v.z == a || v.w == a) {
                int e = i4 >> 1;   // 8 ints per edge, int4 = half an edge
                atomicOr(&colA[e >> 6], 1ULL << (e & 63));
            }
        }
    }
    __syncthreads();
    for (int w = tid; w < W64; w += 512) p.bmT[w * NN + a] = colA[w];

    // ---- embed: h0 = gelu(LN(x@Wi+bi)) + PE ; hc0 = h0@Wc[0]
    float s0 = 0.0f;
    if (kq == 0) {
        s0 = p.bi[j];
        #pragma unroll
        for (int d = 0; d < DD; ++d) s0 = fmaf(p.x[a * DD + d], p.Wi[d * HH + j], s0);
        sv[j] = s0; sv2[j] = s0 * s0;
    }
    __syncthreads();
    ln_reduce(sv, sv2, mred, tid);
    __syncthreads();
    if (kq == 0) {
        float mean = mred[0], var = mred[1] - mean * mean;
        float v = (s0 - mean) * rsqrtf(var + 1e-5f) * p.lnig[j] + p.lnib[j];
        float ge = geluf(v);
        int i2 = (j >> 1) * 2;
        float div = expf((float)i2 * (-9.210340371976184f / 128.0f));
        float ang = (float)a * div;
        float pe = (j & 1) ? cosf(ang) : sinf(ang);
        hrow[j] = ge + pe;
    }
    __syncthreads();
    {
        float pp = 0.0f; int k0 = kq * 32;
        #pragma unroll 8
        for (int kk = 0; kk < 32; ++kk) pp = fmaf(hrow[k0 + kk], p.Wc[(k0 + kk) * HH + j], pp);
        psA[kq][j] = pp;
    }
    __syncthreads();
    if (kq == 0) p.hc[a * HH + j] = psA[0][j] + psA[1][j] + psA[2][j] + psA[3][j];

    grid.sync();   // bmT + hc visible everywhere

    // ---- prologue 2: G row (popcount) + member-edge list, once, persistent in LDS
    if (tid < NN) {
        int acc = 0;
        #pragma unroll 8
        for (int w = 0; w < W64; ++w) acc += __popcll(colA[w] & p.bmT[w * NN + tid]);
        Gs[tid] = (float)acc;
    }
    {
        unsigned long long w = (tid < W64) ? colA[tid] : 0ULL;
        int c = __popcll(w);
        int lane = tid & 63, wid = tid >> 6;
        int incl = c;
        #pragma unroll
        for (int m = 1; m < 64; m <<= 1) {
            int v = __shfl_up(incl, m);
            if (lane >= m) incl += v;
        }
        if (lane == 63) wsum[wid] = incl;
        __syncthreads();
        if (tid == 0) {
            int ss = 0;
            #pragma unroll
            for (int i = 0; i < 8; ++i) { int v = wsum[i]; wsum[i] = ss; ss += v; }
            wtot = ss;
        }
        __syncthreads();
        int base = wsum[wid] + incl - c;
        while (w) {
            int b = __ffsll((long long)w) - 1;
            w &= w - 1;
            list[base++] = tid * 64 + b;
        }
    }
    __syncthreads();
    const int cnt = wtot;
    const float cntn = fmaxf((float)cnt, 1.0f);

    // ---- layers
    for (int l = 0; l < LL; ++l) {
        const float* Wq = p.Wq + l * HH * HH; const float* bq = p.bq + l * HH;
        const float* Wk = p.Wk + l * HH * HH; const float* bk = p.bk + l * HH;
        const float* Wv = p.Wv + l * HH * HH; const float* bv = p.bv + l * HH;
        const float* Wo = p.Wo + l * HH * HH; const float* bo = p.bo + l * HH;
        const float* Wf1 = p.Wf1 + l * HH * FFD; const float* bf1 = p.bf1 + l * FFD;
        const float* Wf2 = p.Wf2 + l * FFD * HH; const float* bf2 = p.bf2 + l * HH;

        // phase 1: conv (G@hc) + LN1 + QKV, write K,V global
        {
            float pc = 0.0f; int m0 = kq * 50;
            #pragma unroll 5
            for (int mm = 0; mm < 50; ++mm) pc = fmaf(Gs[m0 + mm], p.hc[(m0 + mm) * HH + j], pc);
            psA[kq][j] = pc;
        }
        __syncthreads();
        float val = 0.0f;
        if (kq == 0) {
            float acc = psA[0][j] + psA[1][j] + psA[2][j] + psA[3][j];
            val = hrow[j] + acc / (8.0f * cntn) + p.bc[l * HH + j];
            sv[j] = val; sv2[j] = val * val;
        }
        __syncthreads();
        ln_reduce(sv, sv2, mred, tid);
        __syncthreads();
        if (kq == 0) {
            float mean = mred[0], var = mred[1] - mean * mean;
            row[j] = (val - mean) * rsqrtf(var + 1e-5f) * p.n1g[l * HH + j] + p.n1b[l * HH + j];
        }
        __syncthreads();
        {
            float pq = 0.0f, pk = 0.0f, pv = 0.0f; int k0 = kq * 32;
            #pragma unroll 4
            for (int kk = 0; kk < 32; ++kk) {
                float r = row[k0 + kk]; int idx = (k0 + kk) * HH + j;
                pq = fmaf(r, Wq[idx], pq);
                pk = fmaf(r, Wk[idx], pk);
                pv = fmaf(r, Wv[idx], pv);
            }
            psA[kq][j] = pq; psB[kq][j] = pk; psC[kq][j] = pv;
        }
        __syncthreads();
        if (kq == 0) {
            Qs[j]           = bq[j] + psA[0][j] + psA[1][j] + psA[2][j] + psA[3][j];
            p.K[a * HH + j] = bk[j] + psB[0][j] + psB[1][j] + psB[2][j] + psB[3][j];
            p.V[a * HH + j] = bv[j] + psC[0][j] + psC[1][j] + psC[2][j] + psC[3][j];
        }
        grid.sync();

        // phase 2: logits, softmax-scatter, W@V, Wo, FFN, LN2, next hc
        for (int t = tid; t < NHEAD * NN; t += 512) Wrow[t] = 0;
        for (int task = tid; task < 1024; task += 512) {
            int hh = task >> 8, b = task & 255;
            if (b < NN) {
                const float4* kp4 = (const float4*)(p.K + b * HH + hh * HDIM);
                const float4* qp4 = (const float4*)(Qs + hh * HDIM);
                float acc = 0.0f;
                #pragma unroll
                for (int u = 0; u < 8; ++u) {
                    float4 kv = kp4[u], qv = qp4[u];
                    acc += qv.x * kv.x + qv.y * kv.y + qv.z * kv.z + qv.w * kv.w;
                }
                Ts[hh * NN + b] = acc * RSCALE;
            }
        }
        __syncthreads();
        int ntask = cnt * NHEAD;
        for (int t = tid; t < ntask; t += 512) {
            int m = t >> 2, hh = t & 3;
            int e = list[m];
            int4 e0 = ((const int4*)p.hedges)[e * 2];
            int4 e1 = ((const int4*)p.hedges)[e * 2 + 1];
            const float* Tr = Ts + hh * NN;
            float l0 = Tr[e0.x], l1 = Tr[e0.y], l2 = Tr[e0.z], l3 = Tr[e0.w];
            float l4 = Tr[e1.x], l5 = Tr[e1.y], l6 = Tr[e1.z], l7 = Tr[e1.w];
            float mx = fmaxf(fmaxf(fmaxf(l0, l1), fmaxf(l2, l3)),
                             fmaxf(fmaxf(l4, l5), fmaxf(l6, l7)));
            l0 = __expf(l0 - mx); l1 = __expf(l1 - mx); l2 = __expf(l2 - mx); l3 = __expf(l3 - mx);
            l4 = __expf(l4 - mx); l5 = __expf(l5 - mx); l6 = __expf(l6 - mx); l7 = __expf(l7 - mx);
            float inv = WSCALE / (l0 + l1 + l2 + l3 + l4 + l5 + l6 + l7);
            int* Wr = Wrow + hh * NN;
            atomicAdd(&Wr[e0.x], __float2int_rn(l0 * inv));
            atomicAdd(&Wr[e0.y], __float2int_rn(l1 * inv));
            atomicAdd(&Wr[e0.z], __float2int_rn(l2 * inv));
            atomicAdd(&Wr[e0.w], __float2int_rn(l3 * inv));
            atomicAdd(&Wr[e1.x], __float2int_rn(l4 * inv));
            atomicAdd(&Wr[e1.y], __float2int_rn(l5 * inv));
            atomicAdd(&Wr[e1.z], __float2int_rn(l6 * inv));
            atomicAdd(&Wr[e1.w], __float2int_rn(l7 * inv));
        }
        __syncthreads();
        {
            int sc = tid >> 7, hh = (tid >> 5) & 3, d = tid & 31;
            float acc = 0.0f; int b0 = sc * 50;
            #pragma unroll 5
            for (int bb = 0; bb < 50; ++bb) {
                int b = b0 + bb;
                acc = fmaf((float)Wrow[hh * NN + b], p.V[b * HH + hh * HDIM + d], acc);
            }
            psA[sc][hh * HDIM + d] = acc;
        }
        __syncthreads();
        if (tid < HH) aggs[tid] = (psA[0][tid] + psA[1][tid] + psA[2][tid] + psA[3][tid]) * WNORM / cntn;
        __syncthreads();
        {
            float pp = 0.0f; int k0 = kq * 32;
            #pragma unroll 8
            for (int kk = 0; kk < 32; ++kk) pp = fmaf(aggs[k0 + kk], Wo[(k0 + kk) * HH + j], pp);
            psA[kq][j] = pp;
        }
        __syncthreads();
        if (tid < HH) h2s[tid] = row[tid] + bo[tid] + psA[0][tid] + psA[1][tid] + psA[2][tid] + psA[3][tid];
        __syncthreads();
        {
            float tval = bf1[tid];
            #pragma unroll 8
            for (int k = 0; k < HH; ++k) tval = fmaf(h2s[k], Wf1[k * FFD + tid], tval);
            ts[tid] = geluf(tval);
        }
        __syncthreads();
        {
            float pp = 0.0f; int f0 = kq * 128;
            #pragma unroll 8
            for (int ff = 0; ff < 128; ++ff) pp = fmaf(ts[f0 + ff], Wf2[(f0 + ff) * HH + j], pp);
            psA[kq][j] = pp;
        }
        __syncthreads();
        float o = 0.0f;
        if (kq == 0) {
            o = h2s[j] + bf2[j] + psA[0][j] + psA[1][j] + psA[2][j] + psA[3][j];
            sv[j] = o; sv2[j] = o * o;
        }
        __syncthreads();
        ln_reduce(sv, sv2, mred, tid);
        __syncthreads();
        if (kq == 0) {
            float mean = mred[0], var = mred[1] - mean * mean;
            float hv = (o - mean) * rsqrtf(var + 1e-5f) * p.n2g[l * HH + j] + p.n2b[l * HH + j];
            hrow[j] = hv;
            if (l == LL - 1) p.h[a * HH + j] = hv;
        }
        __syncthreads();
        if (l + 1 < LL) {
            const float* WcN = p.Wc + (l + 1) * HH * HH;
            float pp = 0.0f; int k0 = kq * 32;
            #pragma unroll 8
            for (int kk = 0; kk < 32; ++kk) pp = fmaf(hrow[k0 + kk], WcN[(k0 + kk) * HH + j], pp);
            psA[kq][j] = pp;
            __syncthreads();
            if (kq == 0) p.hc[a * HH + j] = psA[0][j] + psA[1][j] + psA[2][j] + psA[3][j];
        }
        grid.sync();
    }

    // ---- final heads: blocks 0-2 = 3 output heads, block 3 = emb
    if (a < 4) {
        {
            float sm = 0.0f, mx = -3.4e38f;
            for (int r = 0; r < 50; ++r) {
                float v = p.h[(kq * 50 + r) * HH + j];
                sm += v; mx = fmaxf(mx, v);
            }
            psA[kq][j] = sm; psB[kq][j] = mx;
        }
        __syncthreads();
        if (tid < HH) {
            float sm = psA[0][j] + psA[1][j] + psA[2][j] + psA[3][j];
            float m = fmaxf(fmaxf(psB[0][j], psB[1][j]), fmaxf(psB[2][j], psB[3][j]));
            ts[j] = sm * (1.0f / NN); ts[HH + j] = m; ts[2 * HH + j] = sm;
        }
        __syncthreads();
        if (a < 3) {
            float pp = 0.0f; int i0 = kq * 96;
            #pragma unroll 8
            for (int ii = 0; ii < 96; ++ii) pp = fmaf(ts[i0 + ii], p.Wh1[a * 49152 + (i0 + ii) * 128 + j], pp);
            psC[kq][j] = pp;
            __syncthreads();
            if (tid < HH) row[j] = geluf(p.bh1[a * 128 + j] + psC[0][j] + psC[1][j] + psC[2][j] + psC[3][j]);
            __syncthreads();
            if (tid < 256) {
                int o2 = tid & 63, sc = tid >> 6;
                float p2 = 0.0f; int i0b = sc * 32;
                #pragma unroll 8
                for (int ii = 0; ii < 32; ++ii) p2 = fmaf(row[i0b + ii], p.Wh2[a * 8192 + (i0b + ii) * 64 + o2], p2);
                psC[sc][o2] = p2;
            }
            __syncthreads();
            if (tid < 64) aggs[tid] = geluf(p.bh2[a * 64 + tid] + psC[0][tid] + psC[1][tid] + psC[2][tid] + psC[3][tid]);
            __syncthreads();
            if (tid < 64) {
                float v = aggs[tid] * p.Wh3[a * 64 + tid];
                #pragma unroll
                for (int m = 32; m > 0; m >>= 1) v += __shfl_xor(v, m);
                if (tid == 0) {
                    float acc = v + p.bh3[a];
                    float r;
                    if (a == 0)      r = softplusf(acc) + 1.0f;
                    else if (a == 1) r = 1.0f / (1.0f + expf(-acc));
                    else             r = softplusf(acc);
                    p.out[a] = r;
                }
            }
        } else {
            float pp = 0.0f; int i0 = kq * 96;
            #pragma unroll 8
            for (int ii = 0; ii < 96; ++ii) pp = fmaf(ts[i0 + ii], p.We[(i0 + ii) * 128 + j], pp);
            psC[kq][j] = pp;
            __syncthreads();
            if (tid < HH) p.out[3 + j] = p.be[j] + psC[0][j] + psC[1][j] + psC[2][j] + psC[3][j];
        }
    }
}

// ---------------- launch ----------------

extern "C" void kernel_launch(void* const* d_in, const int* in_sizes, int n_in,
                              void* d_out, int out_size, void* d_ws, size_t ws_size,
                              hipStream_t stream) {
    P prm;
    prm.x      = (const float*)d_in[0];
    prm.hedges = (const int*)d_in[1];
    prm.Wi   = (const float*)d_in[2];  prm.bi  = (const float*)d_in[3];
    prm.lnig = (const float*)d_in[4];  prm.lnib = (const float*)d_in[5];
    prm.Wc   = (const float*)d_in[6];  prm.bc  = (const float*)d_in[7];
    prm.Wq   = (const float*)d_in[8];  prm.bq  = (const float*)d_in[9];
    prm.Wk   = (const float*)d_in[10]; prm.bk  = (const float*)d_in[11];
    prm.Wv   = (const float*)d_in[12]; prm.bv  = (const float*)d_in[13];
    prm.Wo   = (const float*)d_in[14]; prm.bo  = (const float*)d_in[15];
    prm.n1g  = (const float*)d_in[16]; prm.n1b = (const float*)d_in[17];
    prm.n2g  = (const float*)d_in[18]; prm.n2b = (const float*)d_in[19];
    prm.Wf1  = (const float*)d_in[20]; prm.bf1 = (const float*)d_in[21];
    prm.Wf2  = (const float*)d_in[22]; prm.bf2 = (const float*)d_in[23];
    prm.Wh1  = (const float*)d_in[24]; prm.bh1 = (const float*)d_in[25];
    prm.Wh2  = (const float*)d_in[26]; prm.bh2 = (const float*)d_in[27];
    prm.Wh3  = (const float*)d_in[28]; prm.bh3 = (const float*)d_in[29];
    prm.We   = (const float*)d_in[30]; prm.be  = (const float*)d_in[31];

    float* ws = (float*)d_ws;
    prm.h   = ws;                 // 25600
    prm.hc  = ws + 25600;         // 25600
    prm.K   = ws + 51200;         // 25600
    prm.V   = ws + 76800;         // 25600
    prm.bmT = (unsigned long long*)(ws + 102400);   // 51200 u64
    prm.out = (float*)d_out;

    void* args[] = { (void*)&prm };
    hipLaunchCooperativeKernel(k_coop, dim3(NN), dim3(512), args, 0, stream);
}

// Round 6
// 198.032 us; speedup vs baseline: 3.0930x; 3.0930x over previous
//
#include <hip/hip_runtime.h>
#include <hip/hip_bf16.h>
#include <math.h>

#define NN 200
#define DD 8
#define HH 128
#define NHEAD 4
#define HDIM 32
#define LL 6
#define EE 16384
#define SS 8
#define FFD 512
#define W64 256                  // EE/64 bitmap words per node column

#define WSCALE 1048576.0f        // 2^20 fixed-point scale for LDS int attention atomics
#define WNORM  (1.0f/1048576.0f)
#define RSCALE 0.17677669529663687f   // 1/sqrt(32)

// ---------------- helpers ----------------

__device__ __forceinline__ float geluf(float x) {
    return 0.5f * x * (1.0f + erff(x * 0.70710678118654752f));
}
__device__ __forceinline__ float softplusf(float x) {
    return (x > 20.0f) ? x : log1pf(expf(x));
}
__device__ __forceinline__ void ln_reduce(const float* sv, const float* sv2, float* mred, int tid) {
    if (tid < 64) {
        float s1 = sv[tid] + sv[tid + 64];
        float s2 = sv2[tid] + sv2[tid + 64];
        #pragma unroll
        for (int m = 32; m > 0; m >>= 1) {
            s1 += __shfl_xor(s1, m);
            s2 += __shfl_xor(s2, m);
        }
        if (tid == 0) { mred[0] = s1 * (1.0f / HH); mred[1] = s2 * (1.0f / HH); }
    }
}

// ---------------- setup ----------------

// bmT[w][n] bit b set iff node n is member of edge w*64+b
__global__ void k_bitmap(const int* __restrict__ hedges, unsigned long long* __restrict__ bmT) {
    int t = blockIdx.x * 256 + threadIdx.x;
    if (t >= EE * SS) return;
    int n = hedges[t];
    int e = t >> 3;
    atomicOr(&bmT[(e >> 6) * NN + n], 1ULL << (e & 63));
}

// Per node a (block): float G row, member-edge list, count. One-time.
__launch_bounds__(1024)
__global__ void k_prep(const unsigned long long* __restrict__ bmT,
                       float* __restrict__ Gf, int* __restrict__ lst, int* __restrict__ cntA) {
    __shared__ unsigned long long colA[W64];
    __shared__ int psG[4][NN];
    __shared__ int wsum[4];
    int a = blockIdx.x, tid = threadIdx.x;
    if (tid < W64) colA[tid] = bmT[tid * NN + a];
    __syncthreads();
    {
        int b = tid & 255, q = tid >> 8;
        if (b < NN) {
            int acc = 0;
            int w0 = q * 64;
            #pragma unroll 8
            for (int w = 0; w < 64; ++w) acc += __popcll(colA[w0 + w] & bmT[(w0 + w) * NN + b]);
            psG[q][b] = acc;
        }
    }
    // list extraction on first 256 threads
    unsigned long long w = 0ULL; int c = 0, incl = 0, lane = tid & 63, wid = tid >> 6;
    if (tid < W64) {
        w = colA[tid];
        c = __popcll(w);
        incl = c;
        #pragma unroll
        for (int m = 1; m < 64; m <<= 1) {
            int v = __shfl_up(incl, m);
            if (lane >= m) incl += v;
        }
        if (lane == 63) wsum[wid] = incl;
    }
    __syncthreads();
    if (tid == 0) {
        int ss = 0;
        #pragma unroll
        for (int i = 0; i < 4; ++i) { int v = wsum[i]; wsum[i] = ss; ss += v; }
        cntA[a] = ss;
    }
    if (tid < NN) Gf[a * NN + tid] = (float)(psG[0][tid] + psG[1][tid] + psG[2][tid] + psG[3][tid]);
    __syncthreads();
    if (tid < W64) {
        int base = wsum[wid] + incl - c;
        while (w) {
            int b = __ffsll((long long)w) - 1;
            w &= w - 1;
            lst[a * 1024 + base++] = tid * 64 + b;
        }
    }
}

// ---------------- model kernels ----------------

// h0 = gelu(LN(x@Wi+bi)) + PE ; hc0 = h0 @ Wc[0]     grid: 200 x 512
__launch_bounds__(512)
__global__ void k_embed(const float* __restrict__ x, const float* __restrict__ Wi,
                        const float* __restrict__ bi, const float* __restrict__ lnig,
                        const float* __restrict__ lnib, const float* __restrict__ Wc0,
                        float* __restrict__ h, float* __restrict__ hc) {
    int n = blockIdx.x, tid = threadIdx.x;
    int j = tid & 127, kq = tid >> 7;
    __shared__ float sv[HH], sv2[HH], mred[2], row[HH], psum[4][HH];
    float s = 0.0f;
    if (kq == 0) {
        s = bi[j];
        #pragma unroll
        for (int d = 0; d < DD; ++d) s = fmaf(x[n * DD + d], Wi[d * HH + j], s);
        sv[j] = s; sv2[j] = s * s;
    }
    __syncthreads();
    ln_reduce(sv, sv2, mred, tid);
    __syncthreads();
    if (kq == 0) {
        float mean = mred[0], var = mred[1] - mean * mean;
        float v = (s - mean) * rsqrtf(var + 1e-5f) * lnig[j] + lnib[j];
        float ge = geluf(v);
        int i2 = (j >> 1) * 2;
        float div = expf((float)i2 * (-9.210340371976184f / 128.0f));
        float ang = (float)n * div;
        float pe = (j & 1) ? cosf(ang) : sinf(ang);
        float hv = ge + pe;
        row[j] = hv;
        h[n * HH + j] = hv;
    }
    __syncthreads();
    float p = 0.0f;
    {
        int k0 = kq * 32;
        #pragma unroll 8
        for (int kk = 0; kk < 32; ++kk) p = fmaf(row[k0 + kk], Wc0[(k0 + kk) * HH + j], p);
    }
    psum[kq][j] = p;
    __syncthreads();
    if (kq == 0) hc[n * HH + j] = psum[0][j] + psum[1][j] + psum[2][j] + psum[3][j];
}

// node phase: acc = G@hc ; h1 = LN(h + acc/(8*cnt) + bc) ; Q,K,V = h1@W+b
// grid: 200 x 1024, 8-way split-K
__launch_bounds__(1024)
__global__ void k_node1(const float* __restrict__ h, const float* __restrict__ hc,
                        const float* __restrict__ Gf, const int* __restrict__ cntA,
                        const float* __restrict__ bc,
                        const float* __restrict__ Wq, const float* __restrict__ bq,
                        const float* __restrict__ Wk, const float* __restrict__ bk,
                        const float* __restrict__ Wv, const float* __restrict__ bv,
                        const float* __restrict__ n1g, const float* __restrict__ n1b,
                        float* __restrict__ h1, float* __restrict__ Qo,
                        float* __restrict__ Ko, float* __restrict__ Vo) {
    int n = blockIdx.x, tid = threadIdx.x;
    int j = tid & 127, kq = tid >> 7;            // 8 k-groups
    __shared__ float Gs[NN];
    __shared__ float row[HH];
    __shared__ float psA[8][HH], psB[8][HH], psC[8][HH];
    __shared__ float sv[HH], sv2[HH], mred[2];
    for (int m = tid; m < NN; m += 1024) Gs[m] = Gf[n * NN + m];
    __syncthreads();
    float cntn = fmaxf((float)cntA[n], 1.0f);
    // conv: 8 x 25 split
    {
        float p = 0.0f; int m0 = kq * 25;
        #pragma unroll 5
        for (int mm = 0; mm < 25; ++mm) p = fmaf(Gs[m0 + mm], hc[(m0 + mm) * HH + j], p);
        psA[kq][j] = p;
    }
    __syncthreads();
    float val = 0.0f;
    if (kq == 0) {
        float acc = psA[0][j] + psA[1][j] + psA[2][j] + psA[3][j]
                  + psA[4][j] + psA[5][j] + psA[6][j] + psA[7][j];
        val = h[n * HH + j] + acc / (8.0f * cntn) + bc[j];
        sv[j] = val; sv2[j] = val * val;
    }
    __syncthreads();
    ln_reduce(sv, sv2, mred, tid);
    __syncthreads();
    if (kq == 0) {
        float mean = mred[0], var = mred[1] - mean * mean;
        float hv = (val - mean) * rsqrtf(var + 1e-5f) * n1g[j] + n1b[j];
        row[j] = hv;
        h1[n * HH + j] = hv;
    }
    __syncthreads();
    // QKV: 8 x 16 split, 3 accumulators
    {
        float pq = 0.0f, pk = 0.0f, pv = 0.0f; int k0 = kq * 16;
        #pragma unroll 4
        for (int kk = 0; kk < 16; ++kk) {
            float r = row[k0 + kk]; int idx = (k0 + kk) * HH + j;
            pq = fmaf(r, Wq[idx], pq);
            pk = fmaf(r, Wk[idx], pk);
            pv = fmaf(r, Wv[idx], pv);
        }
        psA[kq][j] = pq; psB[kq][j] = pk; psC[kq][j] = pv;
    }
    __syncthreads();
    if (kq == 0) {
        Qo[n * HH + j] = bq[j] + psA[0][j] + psA[1][j] + psA[2][j] + psA[3][j]
                                + psA[4][j] + psA[5][j] + psA[6][j] + psA[7][j];
        Ko[n * HH + j] = bk[j] + psB[0][j] + psB[1][j] + psB[2][j] + psB[3][j]
                                + psB[4][j] + psB[5][j] + psB[6][j] + psB[7][j];
        Vo[n * HH + j] = bv[j] + psC[0][j] + psC[1][j] + psC[2][j] + psC[3][j]
                                + psC[4][j] + psC[5][j] + psC[6][j] + psC[7][j];
    }
}

// Fused edge attention + aggregation + Wo + FFN + LN2 + next-layer hc.
// grid: 200 x 1024
__launch_bounds__(1024)
__global__ void k_edgefused(const float* __restrict__ Q, const float* __restrict__ K,
                            const float* __restrict__ V, const int* __restrict__ hedges,
                            const int* __restrict__ lst, const int* __restrict__ cntA,
                            const float* __restrict__ h1,
                            const float* __restrict__ Wo, const float* __restrict__ bo,
                            const float* __restrict__ Wf1, const float* __restrict__ bf1,
                            const float* __restrict__ Wf2, const float* __restrict__ bf2,
                            const float* __restrict__ n2g, const float* __restrict__ n2b,
                            const float* __restrict__ WcN,
                            float* __restrict__ h, float* __restrict__ hc) {
    __shared__ float Ts[NHEAD * NN];
    __shared__ int   Wrow[NHEAD * NN];
    __shared__ int   list[1024];
    __shared__ float Qs[HH];
    __shared__ float psum[8][HH];
    __shared__ float psF[2][FFD];
    __shared__ float ts[FFD];
    __shared__ float sv[HH], sv2[HH], mred[2];
    __shared__ float aggs[HH], h2s[HH], rowN[HH];

    int a = blockIdx.x, tid = threadIdx.x;
    int j = tid & 127, kq = tid >> 7;
    int cnt = cntA[a];
    float cntn = fmaxf((float)cnt, 1.0f);

    if (tid < HH) Qs[tid] = Q[a * HH + tid];
    if (tid < NHEAD * NN) Wrow[tid] = 0;
    for (int t = tid; t < cnt; t += 1024) list[t] = lst[a * 1024 + t];
    __syncthreads();

    // logits Ts[h][b] = (q_a[h].k_b[h]) * RSCALE  — one task per thread
    {
        int hh = tid >> 8, b = tid & 255;
        if (b < NN) {
            const float4* kp4 = (const float4*)(K + b * HH + hh * HDIM);
            const float4* qp4 = (const float4*)(Qs + hh * HDIM);
            float acc = 0.0f;
            #pragma unroll
            for (int u = 0; u < 8; ++u) {
                float4 kv = kp4[u], qv = qp4[u];
                acc += qv.x * kv.x + qv.y * kv.y + qv.z * kv.z + qv.w * kv.w;
            }
            Ts[hh * NN + b] = acc * RSCALE;
        }
    }
    __syncthreads();

    // phase A: per (member-edge, head) softmax -> LDS int scatter
    int ntask = cnt * NHEAD;
    for (int t = tid; t < ntask; t += 1024) {
        int m = t >> 2, hh = t & 3;
        int e = list[m];
        int4 e0 = ((const int4*)hedges)[e * 2];
        int4 e1 = ((const int4*)hedges)[e * 2 + 1];
        const float* Tr = Ts + hh * NN;
        float l0 = Tr[e0.x], l1 = Tr[e0.y], l2 = Tr[e0.z], l3 = Tr[e0.w];
        float l4 = Tr[e1.x], l5 = Tr[e1.y], l6 = Tr[e1.z], l7 = Tr[e1.w];
        float mx = fmaxf(fmaxf(fmaxf(l0, l1), fmaxf(l2, l3)),
                         fmaxf(fmaxf(l4, l5), fmaxf(l6, l7)));
        l0 = __expf(l0 - mx); l1 = __expf(l1 - mx); l2 = __expf(l2 - mx); l3 = __expf(l3 - mx);
        l4 = __expf(l4 - mx); l5 = __expf(l5 - mx); l6 = __expf(l6 - mx); l7 = __expf(l7 - mx);
        float inv = WSCALE / (l0 + l1 + l2 + l3 + l4 + l5 + l6 + l7);
        int* Wr = Wrow + hh * NN;
        atomicAdd(&Wr[e0.x], __float2int_rn(l0 * inv));
        atomicAdd(&Wr[e0.y], __float2int_rn(l1 * inv));
        atomicAdd(&Wr[e0.z], __float2int_rn(l2 * inv));
        atomicAdd(&Wr[e0.w], __float2int_rn(l3 * inv));
        atomicAdd(&Wr[e1.x], __float2int_rn(l4 * inv));
        atomicAdd(&Wr[e1.y], __float2int_rn(l5 * inv));
        atomicAdd(&Wr[e1.z], __float2int_rn(l6 * inv));
        atomicAdd(&Wr[e1.w], __float2int_rn(l7 * inv));
    }
    __syncthreads();

    // phase B: agg = (Wrow@V)/cnt — 8 x 25 split over b
    {
        int hh = (tid >> 5) & 3, d = tid & 31;
        float acc = 0.0f; int b0 = kq * 25;
        #pragma unroll 5
        for (int bb = 0; bb < 25; ++bb) {
            int b = b0 + bb;
            acc = fmaf((float)Wrow[hh * NN + b], V[b * HH + hh * HDIM + d], acc);
        }
        psum[kq][j] = acc;   // j == hh*32+d
    }
    __syncthreads();
    if (tid < HH) aggs[tid] = (psum[0][tid] + psum[1][tid] + psum[2][tid] + psum[3][tid]
                             + psum[4][tid] + psum[5][tid] + psum[6][tid] + psum[7][tid]) * WNORM / cntn;
    __syncthreads();
    // h2 = h1 + agg@Wo + bo — 8 x 16 split
    {
        float p = 0.0f; int k0 = kq * 16;
        #pragma unroll 8
        for (int kk = 0; kk < 16; ++kk) p = fmaf(aggs[k0 + kk], Wo[(k0 + kk) * HH + j], p);
        psum[kq][j] = p;
    }
    __syncthreads();
    if (tid < HH) h2s[tid] = h1[a * HH + tid] + bo[tid]
        + psum[0][tid] + psum[1][tid] + psum[2][tid] + psum[3][tid]
        + psum[4][tid] + psum[5][tid] + psum[6][tid] + psum[7][tid];
    __syncthreads();
    // FFN1: 512 outputs x 2-way split-K (64 each)
    {
        int f = tid & 511, hf = tid >> 9;
        float tval = 0.0f; int k0 = hf * 64;
        #pragma unroll 8
        for (int kk = 0; kk < 64; ++kk) tval = fmaf(h2s[k0 + kk], Wf1[(k0 + kk) * FFD + f], tval);
        psF[hf][f] = tval;
    }
    __syncthreads();
    if (tid < FFD) ts[tid] = geluf(bf1[tid] + psF[0][tid] + psF[1][tid]);
    __syncthreads();
    // FFN2: 8 x 64 split
    {
        float p = 0.0f; int f0 = kq * 64;
        #pragma unroll 8
        for (int ff = 0; ff < 64; ++ff) p = fmaf(ts[f0 + ff], Wf2[(f0 + ff) * HH + j], p);
        psum[kq][j] = p;
    }
    __syncthreads();
    float o = 0.0f;
    if (kq == 0) {
        o = h2s[j] + bf2[j] + psum[0][j] + psum[1][j] + psum[2][j] + psum[3][j]
                  + psum[4][j] + psum[5][j] + psum[6][j] + psum[7][j];
        sv[j] = o; sv2[j] = o * o;
    }
    __syncthreads();
    ln_reduce(sv, sv2, mred, tid);
    __syncthreads();
    if (kq == 0) {
        float mean = mred[0], var = mred[1] - mean * mean;
        float hv = (o - mean) * rsqrtf(var + 1e-5f) * n2g[j] + n2b[j];
        rowN[j] = hv;
        h[a * HH + j] = hv;
    }
    __syncthreads();
    if (WcN) {
        float p = 0.0f; int k0 = kq * 16;
        #pragma unroll 8
        for (int kk = 0; kk < 16; ++kk) p = fmaf(rowN[k0 + kk], WcN[(k0 + kk) * HH + j], p);
        psum[kq][j] = p;
        __syncthreads();
        if (kq == 0) hc[a * HH + j] = psum[0][j] + psum[1][j] + psum[2][j] + psum[3][j]
                                    + psum[4][j] + psum[5][j] + psum[6][j] + psum[7][j];
    }
}

// Pool + heads + emb, 4 blocks x 512
__launch_bounds__(512)
__global__ void k_final4(const float* __restrict__ h,
                         const float* __restrict__ Wh1, const float* __restrict__ bh1,
                         const float* __restrict__ Wh2, const float* __restrict__ bh2,
                         const float* __restrict__ Wh3, const float* __restrict__ bh3,
                         const float* __restrict__ We, const float* __restrict__ be,
                         float* __restrict__ out) {
    __shared__ float gs[384];
    __shared__ float pm[4][HH], px[4][HH];
    __shared__ float psum[4][HH];
    __shared__ float t1s[HH];
    __shared__ float t2s[64];
    int tid = threadIdx.x, j = tid & 127, kq = tid >> 7, kb = blockIdx.x;
    {
        float sm = 0.0f, mx = -3.4e38f;
        for (int r = 0; r < 50; ++r) {
            float v = h[(kq * 50 + r) * HH + j];
            sm += v; mx = fmaxf(mx, v);
        }
        pm[kq][j] = sm; px[kq][j] = mx;
    }
    __syncthreads();
    if (tid < HH) {
        float s = pm[0][j] + pm[1][j] + pm[2][j] + pm[3][j];
        float m = fmaxf(fmaxf(px[0][j], px[1][j]), fmaxf(px[2][j], px[3][j]));
        gs[j] = s * (1.0f / NN); gs[HH + j] = m; gs[2 * HH + j] = s;
    }
    __syncthreads();
    if (kb < 3) {
        float p = 0.0f;
        int i0 = kq * 96;
        #pragma unroll 8
        for (int ii = 0; ii < 96; ++ii) p = fmaf(gs[i0 + ii], Wh1[kb * 49152 + (i0 + ii) * 128 + j], p);
        psum[kq][j] = p;
        __syncthreads();
        if (tid < HH) t1s[j] = geluf(bh1[kb * 128 + j] + psum[0][j] + psum[1][j] + psum[2][j] + psum[3][j]);
        __syncthreads();
        if (tid < 256) {
            int o = tid & 63, sc = tid >> 6;
            float p2 = 0.0f;
            int i0b = sc * 32;
            #pragma unroll 8
            for (int ii = 0; ii < 32; ++ii) p2 = fmaf(t1s[i0b + ii], Wh2[kb * 8192 + (i0b + ii) * 64 + o], p2);
            psum[sc][o] = p2;
        }
        __syncthreads();
        if (tid < 64) t2s[tid] = geluf(bh2[kb * 64 + tid] + psum[0][tid] + psum[1][tid] + psum[2][tid] + psum[3][tid]);
        __syncthreads();
        if (tid < 64) {
            float v = t2s[tid] * Wh3[kb * 64 + tid];
            #pragma unroll
            for (int m = 32; m > 0; m >>= 1) v += __shfl_xor(v, m);
            if (tid == 0) {
                float acc = v + bh3[kb];
                float r;
                if (kb == 0)      r = softplusf(acc) + 1.0f;
                else if (kb == 1) r = 1.0f / (1.0f + expf(-acc));
                else              r = softplusf(acc);
                out[kb] = r;
            }
        }
    } else {
        float p = 0.0f;
        int i0 = kq * 96;
        #pragma unroll 8
        for (int ii = 0; ii < 96; ++ii) p = fmaf(gs[i0 + ii], We[(i0 + ii) * 128 + j], p);
        psum[kq][j] = p;
        __syncthreads();
        if (tid < HH) out[3 + j] = be[j] + psum[0][j] + psum[1][j] + psum[2][j] + psum[3][j];
    }
}

// ---------------- launch ----------------

extern "C" void kernel_launch(void* const* d_in, const int* in_sizes, int n_in,
                              void* d_out, int out_size, void* d_ws, size_t ws_size,
                              hipStream_t stream) {
    const float* x      = (const float*)d_in[0];
    const int*   hedges = (const int*)d_in[1];
    const float* Wi     = (const float*)d_in[2];
    const float* bi     = (const float*)d_in[3];
    const float* lnig   = (const float*)d_in[4];
    const float* lnib   = (const float*)d_in[5];
    const float* Wc     = (const float*)d_in[6];
    const float* bc     = (const float*)d_in[7];
    const float* Wq     = (const float*)d_in[8];
    const float* bq     = (const float*)d_in[9];
    const float* Wk     = (const float*)d_in[10];
    const float* bk     = (const float*)d_in[11];
    const float* Wv     = (const float*)d_in[12];
    const float* bv     = (const float*)d_in[13];
    const float* Wo     = (const float*)d_in[14];
    const float* bo     = (const float*)d_in[15];
    const float* n1g    = (const float*)d_in[16];
    const float* n1b    = (const float*)d_in[17];
    const float* n2g    = (const float*)d_in[18];
    const float* n2b    = (const float*)d_in[19];
    const float* Wf1    = (const float*)d_in[20];
    const float* bf1    = (const float*)d_in[21];
    const float* Wf2    = (const float*)d_in[22];
    const float* bf2    = (const float*)d_in[23];
    const float* Wh1    = (const float*)d_in[24];
    const float* bh1    = (const float*)d_in[25];
    const float* Wh2    = (const float*)d_in[26];
    const float* bh2    = (const float*)d_in[27];
    const float* Wh3    = (const float*)d_in[28];
    const float* bh3    = (const float*)d_in[29];
    const float* We     = (const float*)d_in[30];
    const float* be     = (const float*)d_in[31];

    float* ws = (float*)d_ws;
    float* h    = ws;                          // 25600
    float* h1   = ws + 25600;                  // 25600
    float* hc   = ws + 51200;                  // 25600
    float* Q    = ws + 76800;                  // 25600
    float* K    = ws + 102400;                 // 25600
    float* V    = ws + 128000;                 // 25600
    float* Gf   = ws + 153600;                 // 40000
    unsigned long long* bmT = (unsigned long long*)(ws + 193600);  // 51200 u64
    int*   lst  = (int*)(ws + 296000);         // 200*1024 ints
    int*   cntA = (int*)(ws + 500800);         // 256 ints

    hipMemsetAsync(bmT, 0, (size_t)W64 * NN * sizeof(unsigned long long), stream);
    k_bitmap<<<(EE * SS) / 256, 256, 0, stream>>>(hedges, bmT);
    k_prep<<<NN, 1024, 0, stream>>>(bmT, Gf, lst, cntA);
    k_embed<<<NN, 512, 0, stream>>>(x, Wi, bi, lnig, lnib, Wc, h, hc);

    for (int l = 0; l < LL; ++l) {
        k_node1<<<NN, 1024, 0, stream>>>(h, hc, Gf, cntA,
            bc + l * HH,
            Wq + l * HH * HH, bq + l * HH,
            Wk + l * HH * HH, bk + l * HH,
            Wv + l * HH * HH, bv + l * HH,
            n1g + l * HH, n1b + l * HH,
            h1, Q, K, V);
        const float* WcN = (l + 1 < LL) ? (Wc + (l + 1) * HH * HH) : nullptr;
        k_edgefused<<<NN, 1024, 0, stream>>>(Q, K, V, hedges, lst, cntA, h1,
            Wo + l * HH * HH, bo + l * HH,
            Wf1 + l * HH * FFD, bf1 + l * FFD,
            Wf2 + l * FFD * HH, bf2 + l * HH,
            n2g + l * HH, n2b + l * HH,
            WcN, h, hc);
    }

    k_final4<<<4, 512, 0, stream>>>(h, Wh1, bh1, Wh2, bh2, Wh3, bh3, We, be, (float*)d_out);
}